// Round 4
// baseline (581.506 us; speedup 1.0000x reference)
//
#include <hip/hip_runtime.h>
#include <stdint.h>

// Problem constants
#define BROWS 16384
#define FDIM  2048
#define NCLS  14
#define ADIM  64
#define QKN   1792   // 2*C*D

typedef __attribute__((ext_vector_type(8))) short bhalf8_t;   // 8 bf16 (4 VGPRs)
typedef __attribute__((ext_vector_type(4))) float f32x4_t;    // MFMA C/D frag

__device__ __forceinline__ unsigned short f2bf(float f) {
  unsigned int u = __builtin_bit_cast(unsigned int, f);
  u += 0x7fffu + ((u >> 16) & 1u);      // RNE
  return (unsigned short)(u >> 16);
}
__device__ __forceinline__ float bf2f(unsigned short s) {
  return __builtin_bit_cast(float, (unsigned int)s << 16);
}

__device__ __forceinline__ void gl_lds16(const void* g, void* l) {
  __builtin_amdgcn_global_load_lds(
      (const __attribute__((address_space(1))) unsigned int*)g,
      (__attribute__((address_space(3))) unsigned int*)l, 16, 0, 0);
}

// raw barrier with compiler memory fence (NOT __syncthreads: no vmcnt(0) drain)
#define BAR() do { \
    asm volatile("" ::: "memory"); \
    __builtin_amdgcn_s_barrier(); \
    asm volatile("" ::: "memory"); \
  } while (0)

// ---------------- fused cast: features || W_proj || W_qk || W_fc -> bf16 ----------------
// dst regions are contiguous in workspace, so dst = base + t*8 for all ranges.
#define CN1 4194304   // features 16384*2048/8
#define CN2 524288    // W_proj   2048*2048/8
#define CN3 458752    // W_qk     1792*2048/8
#define CN4 3584      // W_fc     14*2048/8
// total 5,180,928 = 20238 * 256 exactly

__global__ void cast_all(const float* __restrict__ f, const float* __restrict__ wp,
                         const float* __restrict__ wqk, const float* __restrict__ wf,
                         unsigned short* __restrict__ dst) {
  int t = blockIdx.x * 256 + threadIdx.x;
  const float* src;
  if (t < CN1) src = f + (size_t)t * 8;
  else if (t < CN1 + CN2) src = wp + ((size_t)t - CN1) * 8;
  else if (t < CN1 + CN2 + CN3) src = wqk + ((size_t)t - CN1 - CN2) * 8;
  else src = wf + ((size_t)t - CN1 - CN2 - CN3) * 8;
  float4 a = ((const float4*)src)[0], b = ((const float4*)src)[1];
  bhalf8_t o;
  o[0] = f2bf(a.x); o[1] = f2bf(a.y); o[2] = f2bf(a.z); o[3] = f2bf(a.w);
  o[4] = f2bf(b.x); o[5] = f2bf(b.y); o[6] = f2bf(b.z); o[7] = f2bf(b.w);
  *((bhalf8_t*)dst + t) = o;
}

// ---------------- fc logits: [B,14] = featC @ WfC^T + b_fc (bf16 in, fp32 acc) ----------
// 1024 blocks x 256 thr; 4 waves/block, 4 rows/wave. WfC staged in LDS (56 KB ->
// 2 blocks/CU). Also zeroes colsum||colsq (16 KB) from blocks 0..3 (runs before GEMM1).
__global__ __launch_bounds__(256) void fc_logits(
    const unsigned short* __restrict__ featC, const unsigned short* __restrict__ WfC,
    const float* __restrict__ bfc, float* __restrict__ logits, float* __restrict__ colzero)
{
  __shared__ unsigned short lWf[NCLS * FDIM];   // 57,344 B
  if (blockIdx.x < 4)
    ((float4*)colzero)[blockIdx.x * 256 + (int)threadIdx.x] = (float4){0.f, 0.f, 0.f, 0.f};
  {
    const bhalf8_t* s = (const bhalf8_t*)WfC;
    bhalf8_t* d = (bhalf8_t*)lWf;
#pragma unroll
    for (int k = 0; k < 14; ++k)                // 14*256*8 = 28672 shorts
      d[k * 256 + (int)threadIdx.x] = s[k * 256 + (int)threadIdx.x];
  }
  __syncthreads();

  const int lane = threadIdx.x & 63, wv = threadIdx.x >> 6;
  const int rbase = blockIdx.x * 16 + wv * 4;
  float acc[4][NCLS];
#pragma unroll
  for (int i = 0; i < 4; ++i)
#pragma unroll
    for (int c = 0; c < NCLS; ++c) acc[i][c] = 0.f;

#pragma unroll
  for (int w = 0; w < 4; ++w) {
    const int c8 = (w * 64 + lane) * 8;
    float fv[4][8];
#pragma unroll
    for (int i = 0; i < 4; ++i) {
      bhalf8_t fr = *(const bhalf8_t*)(featC + (size_t)(rbase + i) * FDIM + c8);
#pragma unroll
      for (int j = 0; j < 8; ++j) fv[i][j] = bf2f((unsigned short)fr[j]);
    }
#pragma unroll
    for (int c = 0; c < NCLS; ++c) {
      bhalf8_t wr = *(const bhalf8_t*)&lWf[c * FDIM + c8];
      float wv8[8];
#pragma unroll
      for (int j = 0; j < 8; ++j) wv8[j] = bf2f((unsigned short)wr[j]);
#pragma unroll
      for (int i = 0; i < 4; ++i) {
        float s = acc[i][c];
#pragma unroll
        for (int j = 0; j < 8; ++j) s += fv[i][j] * wv8[j];
        acc[i][c] = s;
      }
    }
  }
  // wave-reduce each (row, class)
#pragma unroll
  for (int i = 0; i < 4; ++i)
#pragma unroll
    for (int c = 0; c < NCLS; ++c) {
      float v = acc[i][c];
      v += __shfl_xor(v, 1, 64);  v += __shfl_xor(v, 2, 64);
      v += __shfl_xor(v, 4, 64);  v += __shfl_xor(v, 8, 64);
      v += __shfl_xor(v, 16, 64); v += __shfl_xor(v, 32, 64);
      acc[i][c] = v;
    }
  if (lane == 0) {
#pragma unroll
    for (int i = 0; i < 4; ++i)
#pragma unroll
      for (int c = 0; c < NCLS; ++c)
        logits[(size_t)(rbase + i) * 16 + c] = acc[i][c] + bfc[c];
  }
}

// ---------------- 256x256 8-phase MFMA GEMM (T1+T2+T3+T4+T5) ----------------
// BM=BN=256, BK=64, 512 thr (8 waves 2Mx4N), per-wave 128x64 out, acc[8][4].
// N is an exact multiple of 256 for both GEMMs (2048 / 1792) -> no clamp, and
// grid = 512 (2.0 CU-rounds exact) / 448 (1.75 -> 2 rounds).
// LDS 128 KiB: L[buf][A/B][half][128*64] bf16; chunk^(row&7) XOR swizzle via
// pre-swizzled global source (gl_lds dest linear) + swizzled ds_read address.
// Per K-tile: 4 phases {ds_read frags | stage 1 half-tile | bar |
// setprio(1) 16xMFMA setprio(0) | bar}. One s_waitcnt vmcnt(4) per K-tile (P3):
// in-flight there = B(u+1)x4, A(u+1)x4, B(u+2)x4 = 12 -> drains oldest 8,
// leaves B(u+2) in flight. Tail: clamped dummy stages keep count uniform.
// MODE 0: bf16 h store + bias + BN sum/sumsq atomics.  MODE 1: plain bf16 store.

template<int MODE>
__global__ __launch_bounds__(512, 2) void gemm256_bt(
    const unsigned short* __restrict__ A, const unsigned short* __restrict__ Bw,
    const float* __restrict__ bp,
    unsigned short* __restrict__ Cb,
    float* __restrict__ colsum, float* __restrict__ colsq,
    int K, int lda, int ldb, int ldc)
{
  __shared__ unsigned short L[2][2][2][8192];   // [buf][A/B][half][128*64] = 128 KiB

  const int t = threadIdx.x;
  const int lane = t & 63;
  const int wv = t >> 6;
  const int m = lane & 15, quad = lane >> 4;
  const int wm = wv >> 2, wn = wv & 3;

  // T1: bijective XCD swizzle (grid % 8 == 0 by construction)
  const int nwg = gridDim.x;
  const int wg = ((blockIdx.x & 7) * (nwg >> 3)) + (blockIdx.x >> 3);
  const int bx = wg & 63;                 // M/256 == 64
  const int by = wg >> 6;
  const int rowBase = bx << 8;
  const int colBase = by << 8;

  // ds_read fragment offsets (shorts): row group r=16x+m, slot = chunk^(m&7)
  const int bO = (wn & 1) << 12;          // B 64-row subregion offset (64*64 shorts)
  const int ofs0 = m * 64 + ((quad ^ (m & 7)) << 3);   // k-slice 0: chunk quad
  const int ofs1 = ofs0 ^ 32;                          // k-slice 1: chunk quad+4

  // staging: slot s = i*512 + t; r = s>>3, stored chunk = (s&7)^(r&7)
  const int r0 = t >> 3;
  const int q8 = ((t ^ r0) & 7) << 3;     // source chunk element offset in row
  const int ldD = t << 3;                 // LDS dest (shorts); second issue +4096
  const unsigned int aOff =
      (unsigned int)(rowBase + r0) * (unsigned int)lda + (unsigned int)q8;
  const unsigned int bOff00 = (unsigned int)(colBase + r0) * (unsigned int)ldb + q8;
  const unsigned int bOff01 = (unsigned int)(colBase + 64 + r0) * (unsigned int)ldb + q8;
  const unsigned int bOff10 = (unsigned int)(colBase + 128 + r0) * (unsigned int)ldb + q8;
  const unsigned int bOff11 = (unsigned int)(colBase + 192 + r0) * (unsigned int)ldb + q8;

#define STAGEA0(b, kb) do { \
    gl_lds16(A + aOff + (unsigned int)(kb), &L[b][0][0][ldD]); \
    gl_lds16(A + aOff + (unsigned int)(64 * lda) + (unsigned int)(kb), &L[b][0][0][ldD + 4096]); \
  } while (0)
#define STAGEA1(b, kb) do { \
    gl_lds16(A + aOff + (unsigned int)(128 * lda) + (unsigned int)(kb), &L[b][0][1][ldD]); \
    gl_lds16(A + aOff + (unsigned int)(192 * lda) + (unsigned int)(kb), &L[b][0][1][ldD + 4096]); \
  } while (0)
#define STAGEB0(b, kb) do { \
    gl_lds16(Bw + bOff00 + (unsigned int)(kb), &L[b][1][0][ldD]); \
    gl_lds16(Bw + bOff01 + (unsigned int)(kb), &L[b][1][0][ldD + 4096]); \
  } while (0)
#define STAGEB1(b, kb) do { \
    gl_lds16(Bw + bOff10 + (unsigned int)(kb), &L[b][1][1][ldD]); \
    gl_lds16(Bw + bOff11 + (unsigned int)(kb), &L[b][1][1][ldD + 4096]); \
  } while (0)

#define RDA(v, roff) \
    v##_0 = *(const bhalf8_t*)&LA[(roff) + ofs0]; \
    v##_1 = *(const bhalf8_t*)&LA[(roff) + ofs1];
#define RDB(v, roff) \
    v##_0 = *(const bhalf8_t*)&LB[(roff) + ofs0]; \
    v##_1 = *(const bhalf8_t*)&LB[(roff) + ofs1];
#define MM(i, j, av, bv) \
    acc[i][j] = __builtin_amdgcn_mfma_f32_16x16x32_bf16(av##_0, bv##_0, acc[i][j], 0, 0, 0); \
    acc[i][j] = __builtin_amdgcn_mfma_f32_16x16x32_bf16(av##_1, bv##_1, acc[i][j], 0, 0, 0);

  f32x4_t acc[8][4];
#pragma unroll
  for (int i = 0; i < 8; ++i)
#pragma unroll
    for (int j = 0; j < 4; ++j) acc[i][j] = (f32x4_t){0.f, 0.f, 0.f, 0.f};

  const int NT = K >> 6;

  // prologue: K0 fully -> buf0; B of K1 -> buf1. vmcnt(4) completes K0 (8 oldest).
  STAGEA0(0, 0);
  STAGEA1(0, 0);
  STAGEB0(0, 0);
  STAGEB1(0, 0);
  {
    const int kb1 = (NT > 1) ? 64 : 0;
    STAGEB0(1, kb1);
    STAGEB1(1, kb1);
  }
  asm volatile("s_waitcnt vmcnt(4)" ::: "memory");
  BAR();

  for (int u = 0; u < NT; ++u) {
    const int buf = u & 1;
    const unsigned short* LA = &L[buf][0][wm][0];
    const unsigned short* LB = &L[buf][1][wn >> 1][bO];
    const int kbA = (u + 1 < NT) ? (u + 1) << 6 : 0;   // tail: clamped dummy
    const int kbB = (u + 2 < NT) ? (u + 2) << 6 : 0;

    bhalf8_t a0_0, a0_1, a1_0, a1_1, a2_0, a2_1, a3_0, a3_1;
    bhalf8_t b0_0, b0_1, b1_0, b1_1, b2_0, b2_1, b3_0, b3_1;

    // ---- P0: rd A rows 0..63 + B rows 0..31; stage A0(u+1) ----
    RDA(a0, 0);     RDA(a1, 1024);  RDA(a2, 2048);  RDA(a3, 3072);
    RDB(b0, 0);     RDB(b1, 1024);
    if (buf) { STAGEA0(0, kbA); } else { STAGEA0(1, kbA); }
    asm volatile("s_waitcnt lgkmcnt(8)" ::: "memory");   // throttle: 12 ds_reads issued
    BAR();
    __builtin_amdgcn_s_setprio(1);
    MM(0, 0, a0, b0); MM(0, 1, a0, b1);
    MM(1, 0, a1, b0); MM(1, 1, a1, b1);
    MM(2, 0, a2, b0); MM(2, 1, a2, b1);
    MM(3, 0, a3, b0); MM(3, 1, a3, b1);
    __builtin_amdgcn_s_setprio(0);
    BAR();

    // ---- P1: rd B rows 32..63; stage A1(u+1) ----
    RDB(b2, 2048);  RDB(b3, 3072);
    if (buf) { STAGEA1(0, kbA); } else { STAGEA1(1, kbA); }
    BAR();
    __builtin_amdgcn_s_setprio(1);
    MM(0, 2, a0, b2); MM(0, 3, a0, b3);
    MM(1, 2, a1, b2); MM(1, 3, a1, b3);
    MM(2, 2, a2, b2); MM(2, 3, a2, b3);
    MM(3, 2, a3, b2); MM(3, 3, a3, b3);
    __builtin_amdgcn_s_setprio(0);
    BAR();

    // ---- P2: rd A rows 64..127 (reuse a-regs); stage B0(u+2) ----
    RDA(a0, 4096);  RDA(a1, 5120);  RDA(a2, 6144);  RDA(a3, 7168);
    if (buf) { STAGEB0(1, kbB); } else { STAGEB0(0, kbB); }
    BAR();
    __builtin_amdgcn_s_setprio(1);
    MM(4, 0, a0, b0); MM(4, 1, a0, b1);
    MM(5, 0, a1, b0); MM(5, 1, a1, b1);
    MM(6, 0, a2, b0); MM(6, 1, a2, b1);
    MM(7, 0, a3, b0); MM(7, 1, a3, b1);
    __builtin_amdgcn_s_setprio(0);
    BAR();

    // ---- P3: stage B1(u+2); counted vmcnt -> iter u+1's 8 loads complete ----
    if (buf) { STAGEB1(1, kbB); } else { STAGEB1(0, kbB); }
    BAR();
    __builtin_amdgcn_s_setprio(1);
    MM(4, 2, a0, b2); MM(4, 3, a0, b3);
    MM(5, 2, a1, b2); MM(5, 3, a1, b3);
    MM(6, 2, a2, b2); MM(6, 3, a2, b3);
    MM(7, 2, a3, b2); MM(7, 3, a3, b3);
    __builtin_amdgcn_s_setprio(0);
    asm volatile("s_waitcnt vmcnt(4)" ::: "memory");
    BAR();
  }
  asm volatile("s_waitcnt vmcnt(0)" ::: "memory");   // drain tail dummies

#undef STAGEA0
#undef STAGEA1
#undef STAGEB0
#undef STAGEB1
#undef RDA
#undef RDB
#undef MM

  // epilogue: C/D layout col = lane&15 (+16*ni +64*wn), row = quad*4 + r (+16*mi +128*wm)
  if (MODE == 0) {
#pragma unroll
    for (int ni = 0; ni < 4; ++ni) {
      const int gcol = colBase + wn * 64 + ni * 16 + m;
      const float bv = bp[gcol];
      float s = 0.f, qq = 0.f;
#pragma unroll
      for (int mi = 0; mi < 8; ++mi) {
        const size_t grow = (size_t)(rowBase + wm * 128 + mi * 16 + quad * 4);
#pragma unroll
        for (int r = 0; r < 4; ++r) {
          float v = acc[mi][ni][r] + bv;
          Cb[(grow + r) * (size_t)ldc + gcol] = f2bf(v);
          s += v; qq += v * v;
        }
      }
      s += __shfl_xor(s, 16, 64); s += __shfl_xor(s, 32, 64);
      qq += __shfl_xor(qq, 16, 64); qq += __shfl_xor(qq, 32, 64);
      if (quad == 0) { atomicAdd(&colsum[gcol], s); atomicAdd(&colsq[gcol], qq); }
    }
  } else {
#pragma unroll
    for (int ni = 0; ni < 4; ++ni) {
      const int gcol = colBase + wn * 64 + ni * 16 + m;
#pragma unroll
      for (int mi = 0; mi < 8; ++mi) {
        const size_t grow = (size_t)(rowBase + wm * 128 + mi * 16 + quad * 4);
#pragma unroll
        for (int r = 0; r < 4; ++r)
          Cb[(grow + r) * (size_t)ldc + gcol] = f2bf(acc[mi][ni][r]);
      }
    }
  }
}

// ---------------- BatchNorm: fused finalize + apply ----------------
// h = bf16(relu(h*scale + shift)) in-place; scale/shift recomputed per thread
// from colsum/colsq (L2-hot 8 KB arrays) -- saves the bn_finalize dispatch.
__global__ void bn_apply(unsigned short* __restrict__ hb,
                         const float* __restrict__ cs, const float* __restrict__ cq,
                         const float* __restrict__ g, const float* __restrict__ bt) {
  int t = blockIdx.x * 256 + threadIdx.x;
  int row = t >> 8;
  int c8 = (t & 255) << 3;
  const float inv = 1.f / (float)BROWS;
  float scv[8], shv[8];
#pragma unroll
  for (int j = 0; j < 8; ++j) {
    float mu = cs[c8 + j] * inv;
    float va = cq[c8 + j] * inv - mu * mu;
    float s = g[c8 + j] * rsqrtf(va + 1e-5f);
    scv[j] = s;
    shv[j] = bt[c8 + j] - mu * s;
  }
  unsigned short* p = hb + (size_t)row * FDIM + c8;
  bhalf8_t v = *(bhalf8_t*)p;
  bhalf8_t o;
#pragma unroll
  for (int j = 0; j < 8; ++j)
    o[j] = f2bf(fmaxf(bf2f((unsigned short)v[j]) * scv[j] + shv[j], 0.f));
  *(bhalf8_t*)p = o;
}

// ---------------- attention epilogue: one wave per row ----------------
__global__ __launch_bounds__(256) void attn_ep(
    const unsigned short* __restrict__ qk, const float* __restrict__ logits,
    const float* __restrict__ gamma, float* __restrict__ out)
{
  const int lane = threadIdx.x & 63;
  const int wv = threadIdx.x >> 6;
  const int b = blockIdx.x * 4 + wv;
  const int m = lane & 15, quad = lane >> 4;
  const unsigned short* qrow = qk + (size_t)b * QKN;
  f32x4_t acc = (f32x4_t){0.f, 0.f, 0.f, 0.f};
#pragma unroll
  for (int ks = 0; ks < 2; ++ks) {
    bhalf8_t af = {0,0,0,0,0,0,0,0}, bf = {0,0,0,0,0,0,0,0};
    if (m < NCLS) {
      af = *(const bhalf8_t*)(qrow + m * 64 + ks * 32 + quad * 8);
      bf = *(const bhalf8_t*)(qrow + 896 + m * 64 + ks * 32 + quad * 8);
    }
    acc = __builtin_amdgcn_mfma_f32_16x16x32_bf16(af, bf, acc, 0, 0, 0);
  }
  float logit_e = (m < NCLS) ? logits[(size_t)b * 16 + m] : 0.f;
  float sig = 1.f / (1.f + __expf(-logit_e));
  float corr[4];
#pragma unroll
  for (int r = 0; r < 4; ++r) {
    int c = quad * 4 + r;
    float diag = __shfl(acc[r], (lane & 48) + c, 64);
    float a = acc[r] - diag;
    float av = (m < NCLS) ? fabsf(a) : 0.f;
    av = fmaxf(av, __shfl_xor(av, 1, 64));
    av = fmaxf(av, __shfl_xor(av, 2, 64));
    av = fmaxf(av, __shfl_xor(av, 4, 64));
    av = fmaxf(av, __shfl_xor(av, 8, 64));
    float v = (m < NCLS) ? (a / av) * sig : 0.f;
    v += __shfl_xor(v, 1, 64);
    v += __shfl_xor(v, 2, 64);
    v += __shfl_xor(v, 4, 64);
    v += __shfl_xor(v, 8, 64);
    corr[r] = v;
  }
  if (m == 0) {
#pragma unroll
    for (int r = 0; r < 4; ++r) {
      int c = quad * 4 + r;
      if (c < NCLS) {
        float lc = logits[(size_t)b * 16 + c];
        out[(size_t)b * NCLS + c] = lc + gamma[c] * corr[r];
      }
    }
  }
}

// ---------------- launch ----------------

extern "C" void kernel_launch(void* const* d_in, const int* in_sizes, int n_in,
                              void* d_out, int out_size, void* d_ws, size_t ws_size,
                              hipStream_t stream) {
  const float* features = (const float*)d_in[0];
  const float* W_proj   = (const float*)d_in[1];
  const float* b_proj   = (const float*)d_in[2];
  const float* bn_gamma = (const float*)d_in[3];
  const float* bn_beta  = (const float*)d_in[4];
  const float* W_qk     = (const float*)d_in[5];
  const float* gamma    = (const float*)d_in[6];
  const float* W_fc     = (const float*)d_in[7];
  const float* b_fc     = (const float*)d_in[8];
  float* out = (float*)d_out;

  char* ws = (char*)d_ws;
  unsigned short* featC   = (unsigned short*)ws;                  //  67,108,864 B
  unsigned short* WpC     = (unsigned short*)(ws + 67108864);     //   8,388,608 B
  unsigned short* WqkC    = (unsigned short*)(ws + 75497472);     //   7,340,032 B
  unsigned short* WfC     = (unsigned short*)(ws + 82837504);     //      57,344 B
  unsigned short* hbuf    = (unsigned short*)(ws + 82894848);     //  67,108,864 B
  unsigned short* qkC     = (unsigned short*)(ws + 150003712);    //  58,720,256 B
  float*          logitsB = (float*)(ws + 208723968);             //   1,048,576 B
  float*          colsum  = (float*)(ws + 209772544);             //       8,192 B
  float*          colsq   = (float*)(ws + 209780736);             //       8,192 B (end 209,788,928)

  // fused cast of all fp32 inputs -> contiguous bf16 region (dst = featC + t*8)
  cast_all<<<20238, 256, 0, stream>>>(features, W_proj, W_qk, W_fc, featC);

  // logits [B,16] fp32 (also zeroes colsum/colsq before GEMM1)
  fc_logits<<<1024, 256, 0, stream>>>(featC, WfC, b_fc, logitsB, colsum);

  // GEMM1: h[B,2048] bf16 (+bias +BN stats atomics); grid 64x8 = 512 = 2.0 rounds
  gemm256_bt<0><<<512, 512, 0, stream>>>(
      featC, WpC, b_proj, hbuf, colsum, colsq, FDIM, FDIM, FDIM, FDIM);

  // BN finalize+apply (relu) in-place on bf16 h
  bn_apply<<<16384, 256, 0, stream>>>(hbuf, colsum, colsq, bn_gamma, bn_beta);

  // GEMM2: qk[B,1792] bf16 = h @ W_qk^T; grid 64x7 = 448
  gemm256_bt<1><<<448, 512, 0, stream>>>(
      hbuf, WqkC, nullptr, qkC, nullptr, nullptr, FDIM, FDIM, FDIM, QKN);

  // attention epilogue (one wave per row)
  attn_ep<<<BROWS / 4, 256, 0, stream>>>(qkC, logitsB, gamma, out);
}

// Round 5
// 544.299 us; speedup vs baseline: 1.0684x; 1.0684x over previous
//
#include <hip/hip_runtime.h>
#include <stdint.h>

// Problem constants
#define BROWS 16384
#define FDIM  2048
#define NCLS  14
#define ADIM  64
#define QKN   1792   // 2*C*D

typedef __attribute__((ext_vector_type(8))) short bhalf8_t;   // 8 bf16 (4 VGPRs)
typedef __attribute__((ext_vector_type(4))) float f32x4_t;    // MFMA C/D frag

__device__ __forceinline__ unsigned short f2bf(float f) {
  unsigned int u = __builtin_bit_cast(unsigned int, f);
  u += 0x7fffu + ((u >> 16) & 1u);      // RNE
  return (unsigned short)(u >> 16);
}
__device__ __forceinline__ float bf2f(unsigned short s) {
  return __builtin_bit_cast(float, (unsigned int)s << 16);
}

__device__ __forceinline__ void gl_lds16(const void* g, void* l) {
  __builtin_amdgcn_global_load_lds(
      (const __attribute__((address_space(1))) unsigned int*)g,
      (__attribute__((address_space(3))) unsigned int*)l, 16, 0, 0);
}

// raw barrier with compiler memory fence (NOT __syncthreads: no vmcnt(0) drain)
#define BAR() do { \
    asm volatile("" ::: "memory"); \
    __builtin_amdgcn_s_barrier(); \
    asm volatile("" ::: "memory"); \
  } while (0)

// ---------------- fused cast: features || W_proj || W_qk || W_fc -> bf16 ----------------
#define CN1 4194304   // features 16384*2048/8
#define CN2 524288    // W_proj   2048*2048/8
#define CN3 458752    // W_qk     1792*2048/8
#define CN4 3584      // W_fc     14*2048/8
// total 5,180,928 = 20238 * 256 exactly

__global__ void cast_all(const float* __restrict__ f, const float* __restrict__ wp,
                         const float* __restrict__ wqk, const float* __restrict__ wf,
                         unsigned short* __restrict__ dst) {
  int t = blockIdx.x * 256 + threadIdx.x;
  const float* src;
  if (t < CN1) src = f + (size_t)t * 8;
  else if (t < CN1 + CN2) src = wp + ((size_t)t - CN1) * 8;
  else if (t < CN1 + CN2 + CN3) src = wqk + ((size_t)t - CN1 - CN2) * 8;
  else src = wf + ((size_t)t - CN1 - CN2 - CN3) * 8;
  float4 a = ((const float4*)src)[0], b = ((const float4*)src)[1];
  bhalf8_t o;
  o[0] = f2bf(a.x); o[1] = f2bf(a.y); o[2] = f2bf(a.z); o[3] = f2bf(a.w);
  o[4] = f2bf(b.x); o[5] = f2bf(b.y); o[6] = f2bf(b.z); o[7] = f2bf(b.w);
  *((bhalf8_t*)dst + t) = o;
}

// ---------------- fc logits: [B,14] = featC @ WfC^T + b_fc (bf16 in, fp32 acc) ----------
__global__ __launch_bounds__(256) void fc_logits(
    const unsigned short* __restrict__ featC, const unsigned short* __restrict__ WfC,
    const float* __restrict__ bfc, float* __restrict__ logits, float* __restrict__ colzero)
{
  __shared__ unsigned short lWf[NCLS * FDIM];   // 57,344 B
  if (blockIdx.x < 4)
    ((float4*)colzero)[blockIdx.x * 256 + (int)threadIdx.x] = (float4){0.f, 0.f, 0.f, 0.f};
  {
    const bhalf8_t* s = (const bhalf8_t*)WfC;
    bhalf8_t* d = (bhalf8_t*)lWf;
#pragma unroll
    for (int k = 0; k < 14; ++k)
      d[k * 256 + (int)threadIdx.x] = s[k * 256 + (int)threadIdx.x];
  }
  __syncthreads();

  const int lane = threadIdx.x & 63, wv = threadIdx.x >> 6;
  const int rbase = blockIdx.x * 16 + wv * 4;
  float acc[4][NCLS];
#pragma unroll
  for (int i = 0; i < 4; ++i)
#pragma unroll
    for (int c = 0; c < NCLS; ++c) acc[i][c] = 0.f;

#pragma unroll
  for (int w = 0; w < 4; ++w) {
    const int c8 = (w * 64 + lane) * 8;
    float fv[4][8];
#pragma unroll
    for (int i = 0; i < 4; ++i) {
      bhalf8_t fr = *(const bhalf8_t*)(featC + (size_t)(rbase + i) * FDIM + c8);
#pragma unroll
      for (int j = 0; j < 8; ++j) fv[i][j] = bf2f((unsigned short)fr[j]);
    }
#pragma unroll
    for (int c = 0; c < NCLS; ++c) {
      bhalf8_t wr = *(const bhalf8_t*)&lWf[c * FDIM + c8];
      float wv8[8];
#pragma unroll
      for (int j = 0; j < 8; ++j) wv8[j] = bf2f((unsigned short)wr[j]);
#pragma unroll
      for (int i = 0; i < 4; ++i) {
        float s = acc[i][c];
#pragma unroll
        for (int j = 0; j < 8; ++j) s += fv[i][j] * wv8[j];
        acc[i][c] = s;
      }
    }
  }
#pragma unroll
  for (int i = 0; i < 4; ++i)
#pragma unroll
    for (int c = 0; c < NCLS; ++c) {
      float v = acc[i][c];
      v += __shfl_xor(v, 1, 64);  v += __shfl_xor(v, 2, 64);
      v += __shfl_xor(v, 4, 64);  v += __shfl_xor(v, 8, 64);
      v += __shfl_xor(v, 16, 64); v += __shfl_xor(v, 32, 64);
      acc[i][c] = v;
    }
  if (lane == 0) {
#pragma unroll
    for (int i = 0; i < 4; ++i)
#pragma unroll
      for (int c = 0; c < NCLS; ++c)
        logits[(size_t)(rbase + i) * 16 + c] = acc[i][c] + bfc[c];
  }
}

// ---------------- 256x256 8-phase MFMA GEMM (T1+T2+T3+T4+T5) ----------------
// BM=BN=256, BK=64, 512 thr (8 waves 2Mx4N), per-wave 128x64 out, acc[8][4].
// XCD swizzle: ROW-panel per XCD (bx = wg/nby) -> A panel (1MB) L2-resident,
// read once chip-wide; B (<=8.4MB) re-read per XCD via L3. nwg % 8 == 0.
// K-loop: 4 phases {ds_read frags | stage 1 half-tile | bar | setprio(1)
// 16xMFMA setprio(0) | bar}; one s_waitcnt vmcnt(4) per K-tile (P3) -> drains
// exactly iter u+1's 8 loads, leaves B(u+2) in flight. Tail: clamped dummies.
// Epilogue: C tile transposed through LDS (128KB buffer == 256x256 bf16 tile)
// with col ^ ((row&7)<<3) short-swizzle -> 16B/lane coalesced global stores.
// MODE 0: +bias +BN sum/sumsq atomics.  MODE 1: plain store.

template<int MODE>
__global__ __launch_bounds__(512, 2) void gemm256_bt(
    const unsigned short* __restrict__ A, const unsigned short* __restrict__ Bw,
    const float* __restrict__ bp,
    unsigned short* __restrict__ Cb,
    float* __restrict__ colsum, float* __restrict__ colsq,
    int K, int lda, int ldb, int ldc, int nby)
{
  __shared__ unsigned short L[2][2][2][8192];   // [buf][A/B][half][128*64] = 128 KiB

  const int t = threadIdx.x;
  const int lane = t & 63;
  const int wv = t >> 6;
  const int m = lane & 15, quad = lane >> 4;
  const int wm = wv >> 2, wn = wv & 3;

  // T1 (row-panel form): XCD k owns wg in [k*nwg/8, (k+1)*nwg/8) -> bx-panel group
  const int nwg = gridDim.x;
  const int wg = ((blockIdx.x & 7) * (nwg >> 3)) + (blockIdx.x >> 3);
  const int bx = wg / nby;
  const int by = wg - bx * nby;
  const int rowBase = bx << 8;
  const int colBase = by << 8;

  // ds_read fragment offsets (shorts): row group r=16x+m, slot = chunk^(m&7)
  const int bO = (wn & 1) << 12;          // B 64-row subregion offset (64*64 shorts)
  const int ofs0 = m * 64 + ((quad ^ (m & 7)) << 3);   // k-slice 0: chunk quad
  const int ofs1 = ofs0 ^ 32;                          // k-slice 1: chunk quad+4

  // staging: slot s = i*512 + t; r = s>>3, stored chunk = (s&7)^(r&7)
  const int r0 = t >> 3;
  const int q8 = ((t ^ r0) & 7) << 3;     // source chunk element offset in row
  const int ldD = t << 3;                 // LDS dest (shorts); second issue +4096
  const unsigned int aOff =
      (unsigned int)(rowBase + r0) * (unsigned int)lda + (unsigned int)q8;
  const unsigned int bOff00 = (unsigned int)(colBase + r0) * (unsigned int)ldb + q8;
  const unsigned int bOff01 = (unsigned int)(colBase + 64 + r0) * (unsigned int)ldb + q8;
  const unsigned int bOff10 = (unsigned int)(colBase + 128 + r0) * (unsigned int)ldb + q8;
  const unsigned int bOff11 = (unsigned int)(colBase + 192 + r0) * (unsigned int)ldb + q8;

#define STAGEA0(b, kb) do { \
    gl_lds16(A + aOff + (unsigned int)(kb), &L[b][0][0][ldD]); \
    gl_lds16(A + aOff + (unsigned int)(64 * lda) + (unsigned int)(kb), &L[b][0][0][ldD + 4096]); \
  } while (0)
#define STAGEA1(b, kb) do { \
    gl_lds16(A + aOff + (unsigned int)(128 * lda) + (unsigned int)(kb), &L[b][0][1][ldD]); \
    gl_lds16(A + aOff + (unsigned int)(192 * lda) + (unsigned int)(kb), &L[b][0][1][ldD + 4096]); \
  } while (0)
#define STAGEB0(b, kb) do { \
    gl_lds16(Bw + bOff00 + (unsigned int)(kb), &L[b][1][0][ldD]); \
    gl_lds16(Bw + bOff01 + (unsigned int)(kb), &L[b][1][0][ldD + 4096]); \
  } while (0)
#define STAGEB1(b, kb) do { \
    gl_lds16(Bw + bOff10 + (unsigned int)(kb), &L[b][1][1][ldD]); \
    gl_lds16(Bw + bOff11 + (unsigned int)(kb), &L[b][1][1][ldD + 4096]); \
  } while (0)

#define RDA(v, roff) \
    v##_0 = *(const bhalf8_t*)&LA[(roff) + ofs0]; \
    v##_1 = *(const bhalf8_t*)&LA[(roff) + ofs1];
#define RDB(v, roff) \
    v##_0 = *(const bhalf8_t*)&LB[(roff) + ofs0]; \
    v##_1 = *(const bhalf8_t*)&LB[(roff) + ofs1];
#define MM(i, j, av, bv) \
    acc[i][j] = __builtin_amdgcn_mfma_f32_16x16x32_bf16(av##_0, bv##_0, acc[i][j], 0, 0, 0); \
    acc[i][j] = __builtin_amdgcn_mfma_f32_16x16x32_bf16(av##_1, bv##_1, acc[i][j], 0, 0, 0);

  f32x4_t acc[8][4];
#pragma unroll
  for (int i = 0; i < 8; ++i)
#pragma unroll
    for (int j = 0; j < 4; ++j) acc[i][j] = (f32x4_t){0.f, 0.f, 0.f, 0.f};

  const int NT = K >> 6;

  // prologue: K0 fully -> buf0; B of K1 -> buf1. vmcnt(4) completes K0 (8 oldest).
  STAGEA0(0, 0);
  STAGEA1(0, 0);
  STAGEB0(0, 0);
  STAGEB1(0, 0);
  {
    const int kb1 = (NT > 1) ? 64 : 0;
    STAGEB0(1, kb1);
    STAGEB1(1, kb1);
  }
  asm volatile("s_waitcnt vmcnt(4)" ::: "memory");
  BAR();

  for (int u = 0; u < NT; ++u) {
    const int buf = u & 1;
    const unsigned short* LA = &L[buf][0][wm][0];
    const unsigned short* LB = &L[buf][1][wn >> 1][bO];
    const int kbA = (u + 1 < NT) ? (u + 1) << 6 : 0;   // tail: clamped dummy
    const int kbB = (u + 2 < NT) ? (u + 2) << 6 : 0;

    bhalf8_t a0_0, a0_1, a1_0, a1_1, a2_0, a2_1, a3_0, a3_1;
    bhalf8_t b0_0, b0_1, b1_0, b1_1, b2_0, b2_1, b3_0, b3_1;

    // ---- P0: rd A rows 0..63 + B rows 0..31; stage A0(u+1) ----
    RDA(a0, 0);     RDA(a1, 1024);  RDA(a2, 2048);  RDA(a3, 3072);
    RDB(b0, 0);     RDB(b1, 1024);
    if (buf) { STAGEA0(0, kbA); } else { STAGEA0(1, kbA); }
    asm volatile("s_waitcnt lgkmcnt(8)" ::: "memory");   // throttle: 12 ds_reads issued
    BAR();
    __builtin_amdgcn_s_setprio(1);
    MM(0, 0, a0, b0); MM(0, 1, a0, b1);
    MM(1, 0, a1, b0); MM(1, 1, a1, b1);
    MM(2, 0, a2, b0); MM(2, 1, a2, b1);
    MM(3, 0, a3, b0); MM(3, 1, a3, b1);
    __builtin_amdgcn_s_setprio(0);
    BAR();

    // ---- P1: rd B rows 32..63; stage A1(u+1) ----
    RDB(b2, 2048);  RDB(b3, 3072);
    if (buf) { STAGEA1(0, kbA); } else { STAGEA1(1, kbA); }
    BAR();
    __builtin_amdgcn_s_setprio(1);
    MM(0, 2, a0, b2); MM(0, 3, a0, b3);
    MM(1, 2, a1, b2); MM(1, 3, a1, b3);
    MM(2, 2, a2, b2); MM(2, 3, a2, b3);
    MM(3, 2, a3, b2); MM(3, 3, a3, b3);
    __builtin_amdgcn_s_setprio(0);
    BAR();

    // ---- P2: rd A rows 64..127 (reuse a-regs); stage B0(u+2) ----
    RDA(a0, 4096);  RDA(a1, 5120);  RDA(a2, 6144);  RDA(a3, 7168);
    if (buf) { STAGEB0(1, kbB); } else { STAGEB0(0, kbB); }
    BAR();
    __builtin_amdgcn_s_setprio(1);
    MM(4, 0, a0, b0); MM(4, 1, a0, b1);
    MM(5, 0, a1, b0); MM(5, 1, a1, b1);
    MM(6, 0, a2, b0); MM(6, 1, a2, b1);
    MM(7, 0, a3, b0); MM(7, 1, a3, b1);
    __builtin_amdgcn_s_setprio(0);
    BAR();

    // ---- P3: stage B1(u+2); counted vmcnt -> iter u+1's 8 loads complete ----
    if (buf) { STAGEB1(1, kbB); } else { STAGEB1(0, kbB); }
    BAR();
    __builtin_amdgcn_s_setprio(1);
    MM(4, 2, a0, b2); MM(4, 3, a0, b3);
    MM(5, 2, a1, b2); MM(5, 3, a1, b3);
    MM(6, 2, a2, b2); MM(6, 3, a2, b3);
    MM(7, 2, a3, b2); MM(7, 3, a3, b3);
    __builtin_amdgcn_s_setprio(0);
    asm volatile("s_waitcnt vmcnt(4)" ::: "memory");
    BAR();
  }
  asm volatile("s_waitcnt vmcnt(0)" ::: "memory");   // drain tail dummies (per-thread LDS slots)
  BAR();                                             // ALL waves drained before LDS reuse

#undef STAGEA0
#undef STAGEA1
#undef STAGEB0
#undef STAGEB1
#undef RDA
#undef RDB
#undef MM

  // ---- epilogue: transpose C tile through LDS, store 16B/lane coalesced ----
  // C/D frag layout: row = wm*128 + mi*16 + quad*4 + r, col = wn*64 + ni*16 + m.
  // LDS slot (shorts): row*256 + (col ^ ((row&7)<<3))  -> b16 writes 2-way (free),
  // b128 reads conflict-free, bijective per 8-row stripe.
  unsigned short* Lc = &L[0][0][0][0];   // 131072 B == 256x256 bf16
  if (MODE == 0) {
#pragma unroll
    for (int ni = 0; ni < 4; ++ni) {
      const int lcol = wn * 64 + ni * 16 + m;
      const int gcol = colBase + lcol;
      const float bv = bp[gcol];
      float s = 0.f, qq = 0.f;
#pragma unroll
      for (int mi = 0; mi < 8; ++mi) {
        const int lrow0 = wm * 128 + mi * 16 + quad * 4;
#pragma unroll
        for (int r = 0; r < 4; ++r) {
          float v = acc[mi][ni][r] + bv;
          const int lrow = lrow0 + r;
          Lc[lrow * 256 + (lcol ^ ((lrow & 7) << 3))] = f2bf(v);
          s += v; qq += v * v;
        }
      }
      s += __shfl_xor(s, 16, 64); s += __shfl_xor(s, 32, 64);
      qq += __shfl_xor(qq, 16, 64); qq += __shfl_xor(qq, 32, 64);
      if (quad == 0) { atomicAdd(&colsum[gcol], s); atomicAdd(&colsq[gcol], qq); }
    }
  } else {
#pragma unroll
    for (int ni = 0; ni < 4; ++ni) {
      const int lcol = wn * 64 + ni * 16 + m;
#pragma unroll
      for (int mi = 0; mi < 8; ++mi) {
        const int lrow0 = wm * 128 + mi * 16 + quad * 4;
#pragma unroll
        for (int r = 0; r < 4; ++r) {
          const int lrow = lrow0 + r;
          Lc[lrow * 256 + (lcol ^ ((lrow & 7) << 3))] = f2bf(acc[mi][ni][r]);
        }
      }
    }
  }
  asm volatile("s_waitcnt lgkmcnt(0)" ::: "memory");
  BAR();
  // 16 iters x 512 thr x 16B = 128KB; lanes -> consecutive 16B chunks (coalesced)
#pragma unroll
  for (int i = 0; i < 16; ++i) {
    const int s = i * 512 + t;
    const int tr = s >> 5;            // tile row 0..255
    const int c16 = s & 31;           // 16B chunk 0..31
    bhalf8_t vv = *(const bhalf8_t*)&Lc[tr * 256 + ((c16 ^ (tr & 7)) << 3)];
    *(bhalf8_t*)&Cb[(size_t)(rowBase + tr) * (size_t)ldc + (size_t)(colBase + (c16 << 3))] = vv;
  }
}

// ---------------- BatchNorm: fused finalize + apply ----------------
__global__ void bn_apply(unsigned short* __restrict__ hb,
                         const float* __restrict__ cs, const float* __restrict__ cq,
                         const float* __restrict__ g, const float* __restrict__ bt) {
  int t = blockIdx.x * 256 + threadIdx.x;
  int row = t >> 8;
  int c8 = (t & 255) << 3;
  const float inv = 1.f / (float)BROWS;
  float scv[8], shv[8];
#pragma unroll
  for (int j = 0; j < 8; ++j) {
    float mu = cs[c8 + j] * inv;
    float va = cq[c8 + j] * inv - mu * mu;
    float s = g[c8 + j] * rsqrtf(va + 1e-5f);
    scv[j] = s;
    shv[j] = bt[c8 + j] - mu * s;
  }
  unsigned short* p = hb + (size_t)row * FDIM + c8;
  bhalf8_t v = *(bhalf8_t*)p;
  bhalf8_t o;
#pragma unroll
  for (int j = 0; j < 8; ++j)
    o[j] = f2bf(fmaxf(bf2f((unsigned short)v[j]) * scv[j] + shv[j], 0.f));
  *(bhalf8_t*)p = o;
}

// ---------------- attention epilogue: one wave per row ----------------
__global__ __launch_bounds__(256) void attn_ep(
    const unsigned short* __restrict__ qk, const float* __restrict__ logits,
    const float* __restrict__ gamma, float* __restrict__ out)
{
  const int lane = threadIdx.x & 63;
  const int wv = threadIdx.x >> 6;
  const int b = blockIdx.x * 4 + wv;
  const int m = lane & 15, quad = lane >> 4;
  const unsigned short* qrow = qk + (size_t)b * QKN;
  f32x4_t acc = (f32x4_t){0.f, 0.f, 0.f, 0.f};
#pragma unroll
  for (int ks = 0; ks < 2; ++ks) {
    bhalf8_t af = {0,0,0,0,0,0,0,0}, bf = {0,0,0,0,0,0,0,0};
    if (m < NCLS) {
      af = *(const bhalf8_t*)(qrow + m * 64 + ks * 32 + quad * 8);
      bf = *(const bhalf8_t*)(qrow + 896 + m * 64 + ks * 32 + quad * 8);
    }
    acc = __builtin_amdgcn_mfma_f32_16x16x32_bf16(af, bf, acc, 0, 0, 0);
  }
  float logit_e = (m < NCLS) ? logits[(size_t)b * 16 + m] : 0.f;
  float sig = 1.f / (1.f + __expf(-logit_e));
  float corr[4];
#pragma unroll
  for (int r = 0; r < 4; ++r) {
    int c = quad * 4 + r;
    float diag = __shfl(acc[r], (lane & 48) + c, 64);
    float a = acc[r] - diag;
    float av = (m < NCLS) ? fabsf(a) : 0.f;
    av = fmaxf(av, __shfl_xor(av, 1, 64));
    av = fmaxf(av, __shfl_xor(av, 2, 64));
    av = fmaxf(av, __shfl_xor(av, 4, 64));
    av = fmaxf(av, __shfl_xor(av, 8, 64));
    float v = (m < NCLS) ? (a / av) * sig : 0.f;
    v += __shfl_xor(v, 1, 64);
    v += __shfl_xor(v, 2, 64);
    v += __shfl_xor(v, 4, 64);
    v += __shfl_xor(v, 8, 64);
    corr[r] = v;
  }
  if (m == 0) {
#pragma unroll
    for (int r = 0; r < 4; ++r) {
      int c = quad * 4 + r;
      if (c < NCLS) {
        float lc = logits[(size_t)b * 16 + c];
        out[(size_t)b * NCLS + c] = lc + gamma[c] * corr[r];
      }
    }
  }
}

// ---------------- launch ----------------

extern "C" void kernel_launch(void* const* d_in, const int* in_sizes, int n_in,
                              void* d_out, int out_size, void* d_ws, size_t ws_size,
                              hipStream_t stream) {
  const float* features = (const float*)d_in[0];
  const float* W_proj   = (const float*)d_in[1];
  const float* b_proj   = (const float*)d_in[2];
  const float* bn_gamma = (const float*)d_in[3];
  const float* bn_beta  = (const float*)d_in[4];
  const float* W_qk     = (const float*)d_in[5];
  const float* gamma    = (const float*)d_in[6];
  const float* W_fc     = (const float*)d_in[7];
  const float* b_fc     = (const float*)d_in[8];
  float* out = (float*)d_out;

  char* ws = (char*)d_ws;
  unsigned short* featC   = (unsigned short*)ws;                  //  67,108,864 B
  unsigned short* WpC     = (unsigned short*)(ws + 67108864);     //   8,388,608 B
  unsigned short* WqkC    = (unsigned short*)(ws + 75497472);     //   7,340,032 B
  unsigned short* WfC     = (unsigned short*)(ws + 82837504);     //      57,344 B
  unsigned short* hbuf    = (unsigned short*)(ws + 82894848);     //  67,108,864 B
  unsigned short* qkC     = (unsigned short*)(ws + 150003712);    //  58,720,256 B
  float*          logitsB = (float*)(ws + 208723968);             //   1,048,576 B
  float*          colsum  = (float*)(ws + 209772544);             //       8,192 B
  float*          colsq   = (float*)(ws + 209780736);             //       8,192 B (end 209,788,928)

  // fused cast of all fp32 inputs -> contiguous bf16 region (dst = featC + t*8)
  cast_all<<<20238, 256, 0, stream>>>(features, W_proj, W_qk, W_fc, featC);

  // logits [B,16] fp32 (also zeroes colsum/colsq before GEMM1)
  fc_logits<<<1024, 256, 0, stream>>>(featC, WfC, b_fc, logitsB, colsum);

  // GEMM1: h[B,2048] bf16 (+bias +BN stats atomics); grid 64x8 = 512 = 2.0 rounds
  gemm256_bt<0><<<512, 512, 0, stream>>>(
      featC, WpC, b_proj, hbuf, colsum, colsq, FDIM, FDIM, FDIM, FDIM, 8);

  // BN finalize+apply (relu) in-place on bf16 h
  bn_apply<<<16384, 256, 0, stream>>>(hbuf, colsum, colsq, bn_gamma, bn_beta);

  // GEMM2: qk[B,1792] bf16 = h @ W_qk^T; grid 64x7 = 448
  gemm256_bt<1><<<448, 512, 0, stream>>>(
      hbuf, WqkC, nullptr, qkC, nullptr, nullptr, FDIM, FDIM, FDIM, QKN, 7);

  // attention epilogue (one wave per row)
  attn_ep<<<BROWS / 4, 256, 0, stream>>>(qkC, logitsB, gamma, out);
}

// Round 7
// 529.569 us; speedup vs baseline: 1.0981x; 1.0278x over previous
//
#include <hip/hip_runtime.h>
#include <stdint.h>

// Round 7: resubmission of the round-6 source after race/bounds/ledger audit.
// Container failure attributed to infra (see session journal R6 post-mortem).

// Problem constants
#define BROWS 16384
#define FDIM  2048
#define NCLS  14
#define ADIM  64
#define QKN   1792   // 2*C*D

typedef __attribute__((ext_vector_type(8))) short bhalf8_t;   // 8 bf16 (4 VGPRs)
typedef __attribute__((ext_vector_type(4))) float f32x4_t;    // MFMA C/D frag

__device__ __forceinline__ unsigned short f2bf(float f) {
  unsigned int u = __builtin_bit_cast(unsigned int, f);
  u += 0x7fffu + ((u >> 16) & 1u);      // RNE
  return (unsigned short)(u >> 16);
}
__device__ __forceinline__ float bf2f(unsigned short s) {
  return __builtin_bit_cast(float, (unsigned int)s << 16);
}

__device__ __forceinline__ void gl_lds16(const void* g, void* l) {
  __builtin_amdgcn_global_load_lds(
      (const __attribute__((address_space(1))) unsigned int*)g,
      (__attribute__((address_space(3))) unsigned int*)l, 16, 0, 0);
}

// raw barrier with compiler memory fence (NOT __syncthreads: no vmcnt(0) drain)
#define BAR() do { \
    asm volatile("" ::: "memory"); \
    __builtin_amdgcn_s_barrier(); \
    asm volatile("" ::: "memory"); \
  } while (0)

// ---------------- fused cast: features || W_proj || W_qk || W_fc -> bf16 ----------------
#define CN1 4194304   // features 16384*2048/8
#define CN2 524288    // W_proj   2048*2048/8
#define CN3 458752    // W_qk     1792*2048/8
#define CN4 3584      // W_fc     14*2048/8
// total 5,180,928 = 20238 * 256 exactly

__global__ void cast_all(const float* __restrict__ f, const float* __restrict__ wp,
                         const float* __restrict__ wqk, const float* __restrict__ wf,
                         unsigned short* __restrict__ dst) {
  int t = blockIdx.x * 256 + threadIdx.x;
  const float* src;
  if (t < CN1) src = f + (size_t)t * 8;
  else if (t < CN1 + CN2) src = wp + ((size_t)t - CN1) * 8;
  else if (t < CN1 + CN2 + CN3) src = wqk + ((size_t)t - CN1 - CN2) * 8;
  else src = wf + ((size_t)t - CN1 - CN2 - CN3) * 8;
  float4 a = ((const float4*)src)[0], b = ((const float4*)src)[1];
  bhalf8_t o;
  o[0] = f2bf(a.x); o[1] = f2bf(a.y); o[2] = f2bf(a.z); o[3] = f2bf(a.w);
  o[4] = f2bf(b.x); o[5] = f2bf(b.y); o[6] = f2bf(b.z); o[7] = f2bf(b.w);
  *((bhalf8_t*)dst + t) = o;
}

// ---------------- fc logits: [B,14] = featC @ WfC^T + b_fc (bf16 in, fp32 acc) ----------
__global__ __launch_bounds__(256) void fc_logits(
    const unsigned short* __restrict__ featC, const unsigned short* __restrict__ WfC,
    const float* __restrict__ bfc, float* __restrict__ logits, float* __restrict__ colzero)
{
  __shared__ unsigned short lWf[NCLS * FDIM];   // 57,344 B
  if (blockIdx.x < 4)
    ((float4*)colzero)[blockIdx.x * 256 + (int)threadIdx.x] = (float4){0.f, 0.f, 0.f, 0.f};
  {
    const bhalf8_t* s = (const bhalf8_t*)WfC;
    bhalf8_t* d = (bhalf8_t*)lWf;
#pragma unroll
    for (int k = 0; k < 14; ++k)
      d[k * 256 + (int)threadIdx.x] = s[k * 256 + (int)threadIdx.x];
  }
  __syncthreads();

  const int lane = threadIdx.x & 63, wv = threadIdx.x >> 6;
  const int rbase = blockIdx.x * 16 + wv * 4;
  float acc[4][NCLS];
#pragma unroll
  for (int i = 0; i < 4; ++i)
#pragma unroll
    for (int c = 0; c < NCLS; ++c) acc[i][c] = 0.f;

#pragma unroll
  for (int w = 0; w < 4; ++w) {
    const int c8 = (w * 64 + lane) * 8;
    float fv[4][8];
#pragma unroll
    for (int i = 0; i < 4; ++i) {
      bhalf8_t fr = *(const bhalf8_t*)(featC + (size_t)(rbase + i) * FDIM + c8);
#pragma unroll
      for (int j = 0; j < 8; ++j) fv[i][j] = bf2f((unsigned short)fr[j]);
    }
#pragma unroll
    for (int c = 0; c < NCLS; ++c) {
      bhalf8_t wr = *(const bhalf8_t*)&lWf[c * FDIM + c8];
      float wv8[8];
#pragma unroll
      for (int j = 0; j < 8; ++j) wv8[j] = bf2f((unsigned short)wr[j]);
#pragma unroll
      for (int i = 0; i < 4; ++i) {
        float s = acc[i][c];
#pragma unroll
        for (int j = 0; j < 8; ++j) s += fv[i][j] * wv8[j];
        acc[i][c] = s;
      }
    }
  }
#pragma unroll
  for (int i = 0; i < 4; ++i)
#pragma unroll
    for (int c = 0; c < NCLS; ++c) {
      float v = acc[i][c];
      v += __shfl_xor(v, 1, 64);  v += __shfl_xor(v, 2, 64);
      v += __shfl_xor(v, 4, 64);  v += __shfl_xor(v, 8, 64);
      v += __shfl_xor(v, 16, 64); v += __shfl_xor(v, 32, 64);
      acc[i][c] = v;
    }
  if (lane == 0) {
#pragma unroll
    for (int i = 0; i < 4; ++i)
#pragma unroll
      for (int c = 0; c < NCLS; ++c)
        logits[(size_t)(rbase + i) * 16 + c] = acc[i][c] + bfc[c];
  }
}

// ---------------- 256x256 MFMA GEMM, 4 single-barrier phases per K-tile ----------------
// BM=BN=256, BK=64, 512 thr (8 waves 2Mx4N), per-wave 128x64 out, acc[8][4].
// ONE barrier per phase (4/tile, was 8). Window W(u,p) = [B(u,p-1) .. B(u,p)]:
//   W0: rdB b0-3 + rdA a0,a1 | stage A0(u+1)->buf^1 | MFMA rows 0,1 | rdA a2,a3 | stage A1(u+1)
//   W1: MFMA rows 2,3 | rdA rows64.. (a-regs reused) | stage B0(u+2)->buf
//   W2: MFMA rows 4,5 | rdA | stage B1(u+2)->buf
//   W3: MFMA rows 6,7 | s_waitcnt vmcnt(4)
// Lifetime safety (all >= 1 full barrier): A(u+1) targets read in W(u-1,*), drained
// < B(u-1,3) < W0. B(u+2) targets read only at W0's rdB, drained < B(u,0) < W1/W2.
// Cross-iter reads(u+1) of staged data: after drain@W3 + B(u,3). Drain ledger:
// leftover 4 [B(u+1)] + 8 issued -> vmcnt(4) completes exactly tile u+1's 8.
// Tail: clamped dummy stages keep counts uniform; vmcnt(0) after loop.
// Epilogue: C tile transposed through LDS (128KB = 256x256 bf16) with
// col ^ ((row&7)<<3) swizzle -> 16B/lane coalesced stores.
// MODE 0: +bias +BN sum/sumsq atomics.  MODE 1: plain store.

template<int MODE>
__global__ __launch_bounds__(512, 2) void gemm256_bt(
    const unsigned short* __restrict__ A, const unsigned short* __restrict__ Bw,
    const float* __restrict__ bp,
    unsigned short* __restrict__ Cb,
    float* __restrict__ colsum, float* __restrict__ colsq,
    int K, int lda, int ldb, int ldc, int nby)
{
  __shared__ unsigned short L[2][2][2][8192];   // [buf][A/B][half][128*64] = 128 KiB

  const int t = threadIdx.x;
  const int lane = t & 63;
  const int wv = t >> 6;
  const int m = lane & 15, quad = lane >> 4;
  const int wm = wv >> 2, wn = wv & 3;

  // T1 (row-panel form): XCD k owns a contiguous bx-panel group; A L2-resident.
  const int nwg = gridDim.x;
  const int wg = ((blockIdx.x & 7) * (nwg >> 3)) + (blockIdx.x >> 3);
  const int bx = wg / nby;
  const int by = wg - bx * nby;
  const int rowBase = bx << 8;
  const int colBase = by << 8;

  // ds_read fragment offsets (shorts): row group r=16x+m, slot = chunk^(m&7)
  const int bO = (wn & 1) << 12;          // B 64-row subregion offset (64*64 shorts)
  const int ofs0 = m * 64 + ((quad ^ (m & 7)) << 3);   // k-slice 0: chunk quad
  const int ofs1 = ofs0 ^ 32;                          // k-slice 1: chunk quad+4

  // staging: slot s = i*512 + t; r = s>>3, stored chunk = (s&7)^(r&7)
  const int r0 = t >> 3;
  const int q8 = ((t ^ r0) & 7) << 3;     // source chunk element offset in row
  const int ldD = t << 3;                 // LDS dest (shorts); second issue +4096
  const unsigned int aOff =
      (unsigned int)(rowBase + r0) * (unsigned int)lda + (unsigned int)q8;
  const unsigned int bOff00 = (unsigned int)(colBase + r0) * (unsigned int)ldb + q8;
  const unsigned int bOff01 = (unsigned int)(colBase + 64 + r0) * (unsigned int)ldb + q8;
  const unsigned int bOff10 = (unsigned int)(colBase + 128 + r0) * (unsigned int)ldb + q8;
  const unsigned int bOff11 = (unsigned int)(colBase + 192 + r0) * (unsigned int)ldb + q8;

#define STAGEA0(b, kb) do { \
    gl_lds16(A + aOff + (unsigned int)(kb), &L[b][0][0][ldD]); \
    gl_lds16(A + aOff + (unsigned int)(64 * lda) + (unsigned int)(kb), &L[b][0][0][ldD + 4096]); \
  } while (0)
#define STAGEA1(b, kb) do { \
    gl_lds16(A + aOff + (unsigned int)(128 * lda) + (unsigned int)(kb), &L[b][0][1][ldD]); \
    gl_lds16(A + aOff + (unsigned int)(192 * lda) + (unsigned int)(kb), &L[b][0][1][ldD + 4096]); \
  } while (0)
#define STAGEB0(b, kb) do { \
    gl_lds16(Bw + bOff00 + (unsigned int)(kb), &L[b][1][0][ldD]); \
    gl_lds16(Bw + bOff01 + (unsigned int)(kb), &L[b][1][0][ldD + 4096]); \
  } while (0)
#define STAGEB1(b, kb) do { \
    gl_lds16(Bw + bOff10 + (unsigned int)(kb), &L[b][1][1][ldD]); \
    gl_lds16(Bw + bOff11 + (unsigned int)(kb), &L[b][1][1][ldD + 4096]); \
  } while (0)

#define RDA(v, roff) \
    v##_0 = *(const bhalf8_t*)&LA[(roff) + ofs0]; \
    v##_1 = *(const bhalf8_t*)&LA[(roff) + ofs1];
#define RDB(v, roff) \
    v##_0 = *(const bhalf8_t*)&LB[(roff) + ofs0]; \
    v##_1 = *(const bhalf8_t*)&LB[(roff) + ofs1];
#define MM(i, j, av, bv) \
    acc[i][j] = __builtin_amdgcn_mfma_f32_16x16x32_bf16(av##_0, bv##_0, acc[i][j], 0, 0, 0); \
    acc[i][j] = __builtin_amdgcn_mfma_f32_16x16x32_bf16(av##_1, bv##_1, acc[i][j], 0, 0, 0);

  f32x4_t acc[8][4];
#pragma unroll
  for (int i = 0; i < 8; ++i)
#pragma unroll
    for (int j = 0; j < 4; ++j) acc[i][j] = (f32x4_t){0.f, 0.f, 0.f, 0.f};

  const int NT = K >> 6;

  // prologue: tile0 fully -> buf0; B of tile1 -> buf1. vmcnt(4) completes tile0.
  STAGEA0(0, 0);
  STAGEA1(0, 0);
  STAGEB0(0, 0);
  STAGEB1(0, 0);
  {
    const int kb1 = (NT > 1) ? 64 : 0;
    STAGEB0(1, kb1);
    STAGEB1(1, kb1);
  }
  asm volatile("s_waitcnt vmcnt(4)" ::: "memory");
  BAR();

  for (int u = 0; u < NT; ++u) {
    const int buf = u & 1;
    const unsigned short* LA = &L[buf][0][wm][0];
    const unsigned short* LB = &L[buf][1][wn >> 1][bO];
    const int kbA = (u + 1 < NT) ? (u + 1) << 6 : 0;   // tail: clamped dummy
    const int kbB = (u + 2 < NT) ? (u + 2) << 6 : 0;

    bhalf8_t a0_0, a0_1, a1_0, a1_1, a2_0, a2_1, a3_0, a3_1;
    bhalf8_t b0_0, b0_1, b1_0, b1_1, b2_0, b2_1, b3_0, b3_1;

    // ---- W0: rd all B + A rows 0..31; stage A0(u+1); MFMA rows 0,1; rd A 32..63; stage A1(u+1)
    RDB(b0, 0);     RDB(b1, 1024);  RDB(b2, 2048);  RDB(b3, 3072);
    RDA(a0, 0);     RDA(a1, 1024);
    if (buf) { STAGEA0(0, kbA); } else { STAGEA0(1, kbA); }
    __builtin_amdgcn_s_setprio(1);
    MM(0, 0, a0, b0); MM(0, 1, a0, b1); MM(0, 2, a0, b2); MM(0, 3, a0, b3);
    MM(1, 0, a1, b0); MM(1, 1, a1, b1); MM(1, 2, a1, b2); MM(1, 3, a1, b3);
    __builtin_amdgcn_s_setprio(0);
    RDA(a2, 2048);  RDA(a3, 3072);
    if (buf) { STAGEA1(0, kbA); } else { STAGEA1(1, kbA); }
    BAR();

    // ---- W1: MFMA rows 2,3; rd A rows 64..95 (reuse a0,a1); stage B0(u+2)
    __builtin_amdgcn_s_setprio(1);
    MM(2, 0, a2, b0); MM(2, 1, a2, b1); MM(2, 2, a2, b2); MM(2, 3, a2, b3);
    MM(3, 0, a3, b0); MM(3, 1, a3, b1); MM(3, 2, a3, b2); MM(3, 3, a3, b3);
    __builtin_amdgcn_s_setprio(0);
    RDA(a0, 4096);  RDA(a1, 5120);
    if (buf) { STAGEB0(1, kbB); } else { STAGEB0(0, kbB); }
    BAR();

    // ---- W2: MFMA rows 4,5; rd A rows 96..127 (reuse a2,a3); stage B1(u+2)
    __builtin_amdgcn_s_setprio(1);
    MM(4, 0, a0, b0); MM(4, 1, a0, b1); MM(4, 2, a0, b2); MM(4, 3, a0, b3);
    MM(5, 0, a1, b0); MM(5, 1, a1, b1); MM(5, 2, a1, b2); MM(5, 3, a1, b3);
    __builtin_amdgcn_s_setprio(0);
    RDA(a2, 6144);  RDA(a3, 7168);
    if (buf) { STAGEB1(1, kbB); } else { STAGEB1(0, kbB); }
    BAR();

    // ---- W3: MFMA rows 6,7; counted drain -> tile u+1's 8 loads complete
    __builtin_amdgcn_s_setprio(1);
    MM(6, 0, a2, b0); MM(6, 1, a2, b1); MM(6, 2, a2, b2); MM(6, 3, a2, b3);
    MM(7, 0, a3, b0); MM(7, 1, a3, b1); MM(7, 2, a3, b2); MM(7, 3, a3, b3);
    __builtin_amdgcn_s_setprio(0);
    asm volatile("s_waitcnt vmcnt(4)" ::: "memory");
    BAR();
  }
  asm volatile("s_waitcnt vmcnt(0)" ::: "memory");   // drain tail dummies
  BAR();                                             // ALL waves drained before LDS reuse

#undef STAGEA0
#undef STAGEA1
#undef STAGEB0
#undef STAGEB1
#undef RDA
#undef RDB
#undef MM

  // ---- epilogue: transpose C tile through LDS, store 16B/lane coalesced ----
  // C/D frag layout: row = wm*128 + mi*16 + quad*4 + r, col = wn*64 + ni*16 + m.
  // LDS slot (shorts): row*256 + (col ^ ((row&7)<<3)) -> b16 writes 2-way (free),
  // b128 reads conflict-free, bijective per 8-row stripe.
  unsigned short* Lc = &L[0][0][0][0];   // 131072 B == 256x256 bf16
  if (MODE == 0) {
#pragma unroll
    for (int ni = 0; ni < 4; ++ni) {
      const int lcol = wn * 64 + ni * 16 + m;
      const int gcol = colBase + lcol;
      const float bv = bp[gcol];
      float s = 0.f, qq = 0.f;
#pragma unroll
      for (int mi = 0; mi < 8; ++mi) {
        const int lrow0 = wm * 128 + mi * 16 + quad * 4;
#pragma unroll
        for (int r = 0; r < 4; ++r) {
          float v = acc[mi][ni][r] + bv;
          const int lrow = lrow0 + r;
          Lc[lrow * 256 + (lcol ^ ((lrow & 7) << 3))] = f2bf(v);
          s += v; qq += v * v;
        }
      }
      s += __shfl_xor(s, 16, 64); s += __shfl_xor(s, 32, 64);
      qq += __shfl_xor(qq, 16, 64); qq += __shfl_xor(qq, 32, 64);
      if (quad == 0) { atomicAdd(&colsum[gcol], s); atomicAdd(&colsq[gcol], qq); }
    }
  } else {
#pragma unroll
    for (int ni = 0; ni < 4; ++ni) {
      const int lcol = wn * 64 + ni * 16 + m;
#pragma unroll
      for (int mi = 0; mi < 8; ++mi) {
        const int lrow0 = wm * 128 + mi * 16 + quad * 4;
#pragma unroll
        for (int r = 0; r < 4; ++r) {
          const int lrow = lrow0 + r;
          Lc[lrow * 256 + (lcol ^ ((lrow & 7) << 3))] = f2bf(acc[mi][ni][r]);
        }
      }
    }
  }
  asm volatile("s_waitcnt lgkmcnt(0)" ::: "memory");
  BAR();
  // 16 iters x 512 thr x 16B = 128KB; lanes -> consecutive 16B chunks (coalesced)
#pragma unroll
  for (int i = 0; i < 16; ++i) {
    const int s = i * 512 + t;
    const int tr = s >> 5;            // tile row 0..255
    const int c16 = s & 31;           // 16B chunk 0..31
    bhalf8_t vv = *(const bhalf8_t*)&Lc[tr * 256 + ((c16 ^ (tr & 7)) << 3)];
    *(bhalf8_t*)&Cb[(size_t)(rowBase + tr) * (size_t)ldc + (size_t)(colBase + (c16 << 3))] = vv;
  }
}

// ---------------- BatchNorm: fused finalize + apply, 4 rows/thread ----------------
// h = bf16(relu(h*scale + shift)) in-place; scale/shift computed ONCE per thread
// (same channels for all 4 rows) -> 1/4 the L2 traffic on cs/cq/g/bt.
__global__ void bn_apply(unsigned short* __restrict__ hb,
                         const float* __restrict__ cs, const float* __restrict__ cq,
                         const float* __restrict__ g, const float* __restrict__ bt) {
  int t = blockIdx.x * 256 + threadIdx.x;   // grid 4096 -> 1,048,576 threads
  int c8 = (t & 255) << 3;
  int row0 = t >> 8;                        // 0..4095
  const float inv = 1.f / (float)BROWS;
  float scv[8], shv[8];
#pragma unroll
  for (int j = 0; j < 8; ++j) {
    float mu = cs[c8 + j] * inv;
    float va = cq[c8 + j] * inv - mu * mu;
    float s = g[c8 + j] * rsqrtf(va + 1e-5f);
    scv[j] = s;
    shv[j] = bt[c8 + j] - mu * s;
  }
#pragma unroll
  for (int rr = 0; rr < 4; ++rr) {
    unsigned short* p = hb + (size_t)(row0 + rr * 4096) * FDIM + c8;
    bhalf8_t v = *(bhalf8_t*)p;
    bhalf8_t o;
#pragma unroll
    for (int j = 0; j < 8; ++j)
      o[j] = f2bf(fmaxf(bf2f((unsigned short)v[j]) * scv[j] + shv[j], 0.f));
    *(bhalf8_t*)p = o;
  }
}

// ---------------- attention epilogue: one wave per row ----------------
__global__ __launch_bounds__(256) void attn_ep(
    const unsigned short* __restrict__ qk, const float* __restrict__ logits,
    const float* __restrict__ gamma, float* __restrict__ out)
{
  const int lane = threadIdx.x & 63;
  const int wv = threadIdx.x >> 6;
  const int b = blockIdx.x * 4 + wv;
  const int m = lane & 15, quad = lane >> 4;
  const unsigned short* qrow = qk + (size_t)b * QKN;
  f32x4_t acc = (f32x4_t){0.f, 0.f, 0.f, 0.f};
#pragma unroll
  for (int ks = 0; ks < 2; ++ks) {
    bhalf8_t af = {0,0,0,0,0,0,0,0}, bf = {0,0,0,0,0,0,0,0};
    if (m < NCLS) {
      af = *(const bhalf8_t*)(qrow + m * 64 + ks * 32 + quad * 8);
      bf = *(const bhalf8_t*)(qrow + 896 + m * 64 + ks * 32 + quad * 8);
    }
    acc = __builtin_amdgcn_mfma_f32_16x16x32_bf16(af, bf, acc, 0, 0, 0);
  }
  float logit_e = (m < NCLS) ? logits[(size_t)b * 16 + m] : 0.f;
  float sig = 1.f / (1.f + __expf(-logit_e));
  float corr[4];
#pragma unroll
  for (int r = 0; r < 4; ++r) {
    int c = quad * 4 + r;
    float diag = __shfl(acc[r], (lane & 48) + c, 64);
    float a = acc[r] - diag;
    float av = (m < NCLS) ? fabsf(a) : 0.f;
    av = fmaxf(av, __shfl_xor(av, 1, 64));
    av = fmaxf(av, __shfl_xor(av, 2, 64));
    av = fmaxf(av, __shfl_xor(av, 4, 64));
    av = fmaxf(av, __shfl_xor(av, 8, 64));
    float v = (m < NCLS) ? (a / av) * sig : 0.f;
    v += __shfl_xor(v, 1, 64);
    v += __shfl_xor(v, 2, 64);
    v += __shfl_xor(v, 4, 64);
    v += __shfl_xor(v, 8, 64);
    corr[r] = v;
  }
  if (m == 0) {
#pragma unroll
    for (int r = 0; r < 4; ++r) {
      int c = quad * 4 + r;
      if (c < NCLS) {
        float lc = logits[(size_t)b * 16 + c];
        out[(size_t)b * NCLS + c] = lc + gamma[c] * corr[r];
      }
    }
  }
}

// ---------------- launch ----------------

extern "C" void kernel_launch(void* const* d_in, const int* in_sizes, int n_in,
                              void* d_out, int out_size, void* d_ws, size_t ws_size,
                              hipStream_t stream) {
  const float* features = (const float*)d_in[0];
  const float* W_proj   = (const float*)d_in[1];
  const float* b_proj   = (const float*)d_in[2];
  const float* bn_gamma = (const float*)d_in[3];
  const float* bn_beta  = (const float*)d_in[4];
  const float* W_qk     = (const float*)d_in[5];
  const float* gamma    = (const float*)d_in[6];
  const float* W_fc     = (const float*)d_in[7];
  const float* b_fc     = (const float*)d_in[8];
  float* out = (float*)d_out;

  char* ws = (char*)d_ws;
  unsigned short* featC   = (unsigned short*)ws;                  //  67,108,864 B
  unsigned short* WpC     = (unsigned short*)(ws + 67108864);     //   8,388,608 B
  unsigned short* WqkC    = (unsigned short*)(ws + 75497472);     //   7,340,032 B
  unsigned short* WfC     = (unsigned short*)(ws + 82837504);     //      57,344 B
  unsigned short* hbuf    = (unsigned short*)(ws + 82894848);     //  67,108,864 B
  unsigned short* qkC     = (unsigned short*)(ws + 150003712);    //  58,720,256 B
  float*          logitsB = (float*)(ws + 208723968);             //   1,048,576 B
  float*          colsum  = (float*)(ws + 209772544);             //       8,192 B
  float*          colsq   = (float*)(ws + 209780736);             //       8,192 B (end 209,788,928)

  // fused cast of all fp32 inputs -> contiguous bf16 region (dst = featC + t*8)
  cast_all<<<20238, 256, 0, stream>>>(features, W_proj, W_qk, W_fc, featC);

  // logits [B,16] fp32 (also zeroes colsum/colsq before GEMM1)
  fc_logits<<<1024, 256, 0, stream>>>(featC, WfC, b_fc, logitsB, colsum);

  // GEMM1: h[B,2048] bf16 (+bias +BN stats atomics); grid 64x8 = 512 = 2.0 rounds
  gemm256_bt<0><<<512, 512, 0, stream>>>(
      featC, WpC, b_proj, hbuf, colsum, colsq, FDIM, FDIM, FDIM, FDIM, 8);

  // BN finalize+apply (relu) in-place on bf16 h
  bn_apply<<<4096, 256, 0, stream>>>(hbuf, colsum, colsq, bn_gamma, bn_beta);

  // GEMM2: qk[B,1792] bf16 = h @ W_qk^T; grid 64x7 = 448
  gemm256_bt<1><<<448, 512, 0, stream>>>(
      hbuf, WqkC, nullptr, qkC, nullptr, nullptr, FDIM, FDIM, FDIM, QKN, 7);

  // attention epilogue (one wave per row)
  attn_ep<<<BROWS / 4, 256, 0, stream>>>(qkC, logitsB, gamma, out);
}

// Round 8
// 519.097 us; speedup vs baseline: 1.1202x; 1.0202x over previous
//
#include <hip/hip_runtime.h>
#include <stdint.h>

// Round 8: (1) GEMM K-loop 4 -> 2 barriers/tile; (2) cast_all + fc_logits fused
// into one prep kernel (features read once as fp32; weights grid-stride cast).

// Problem constants
#define BROWS 16384
#define FDIM  2048
#define NCLS  14
#define ADIM  64
#define QKN   1792   // 2*C*D

typedef __attribute__((ext_vector_type(8))) short bhalf8_t;   // 8 bf16 (4 VGPRs)
typedef __attribute__((ext_vector_type(4))) float f32x4_t;    // MFMA C/D frag

__device__ __forceinline__ unsigned short f2bf(float f) {
  unsigned int u = __builtin_bit_cast(unsigned int, f);
  u += 0x7fffu + ((u >> 16) & 1u);      // RNE
  return (unsigned short)(u >> 16);
}
__device__ __forceinline__ float bf2f(unsigned short s) {
  return __builtin_bit_cast(float, (unsigned int)s << 16);
}

__device__ __forceinline__ void gl_lds16(const void* g, void* l) {
  __builtin_amdgcn_global_load_lds(
      (const __attribute__((address_space(1))) unsigned int*)g,
      (__attribute__((address_space(3))) unsigned int*)l, 16, 0, 0);
}

// raw barrier with compiler memory fence (NOT __syncthreads: no vmcnt(0) drain)
#define BAR() do { \
    asm volatile("" ::: "memory"); \
    __builtin_amdgcn_s_barrier(); \
    asm volatile("" ::: "memory"); \
  } while (0)

#define CVT8(o, x, y) do { \
    o[0] = f2bf(x.x); o[1] = f2bf(x.y); o[2] = f2bf(x.z); o[3] = f2bf(x.w); \
    o[4] = f2bf(y.x); o[5] = f2bf(y.y); o[6] = f2bf(y.z); o[7] = f2bf(y.w); \
  } while (0)

// ---------------- fused prep: weights cast + features cast + fc logits ----------------
#define CN2 524288    // W_proj 2048*2048/8 chunks
#define CN3 458752    // W_qk   1792*2048/8 chunks
#define WCH (CN2 + CN3)   // 983040; WpC || WqkC contiguous in workspace

// 1024 blocks x 256 thr. Per block: 16 feature rows (fp32 read once: cast -> featC
// AND fp32 logits dots vs LDS-staged bf16 W_fc). Weights cast grid-strided.
// Blocks 0..3 zero colsum||colsq (16 KB) before GEMM1.
__global__ __launch_bounds__(256) void prep_fused(
    const float* __restrict__ feat, const float* __restrict__ wp,
    const float* __restrict__ wqk, const float* __restrict__ wf,
    const float* __restrict__ bfc,
    unsigned short* __restrict__ featC, unsigned short* __restrict__ WpC,
    float* __restrict__ logits, float* __restrict__ colzero)
{
  __shared__ unsigned short lWf[NCLS * FDIM];   // 57,344 B -> 2 blocks/CU
  const int tid = threadIdx.x;
  if (blockIdx.x < 4)
    ((float4*)colzero)[blockIdx.x * 256 + tid] = (float4){0.f, 0.f, 0.f, 0.f};

  // stage W_fc fp32 -> bf16 LDS
#pragma unroll
  for (int k = 0; k < NCLS; ++k) {
    const float* s = wf + (size_t)k * FDIM + tid * 8;
    float4 x = ((const float4*)s)[0], y = ((const float4*)s)[1];
    bhalf8_t o; CVT8(o, x, y);
    *(bhalf8_t*)&lWf[k * FDIM + tid * 8] = o;
  }

  // weights cast: W_proj || W_qk -> WpC (contiguous dst), grid-stride
  for (int i = blockIdx.x * 256 + tid; i < WCH; i += 262144) {
    const float* s = (i < CN2) ? wp + (size_t)i * 8 : wqk + ((size_t)i - CN2) * 8;
    float4 x = ((const float4*)s)[0], y = ((const float4*)s)[1];
    bhalf8_t o; CVT8(o, x, y);
    *((bhalf8_t*)WpC + i) = o;
  }
  __syncthreads();   // lWf ready

  // features: fp32 read once -> bf16 featC + fp32 logits partials
  const int lane = tid & 63, wv = tid >> 6;
  const int rbase = blockIdx.x * 16 + wv * 4;
  float acc[4][NCLS];
#pragma unroll
  for (int i = 0; i < 4; ++i)
#pragma unroll
    for (int c = 0; c < NCLS; ++c) acc[i][c] = 0.f;

#pragma unroll
  for (int w = 0; w < 4; ++w) {
    const int c8 = (w * 64 + lane) * 8;
    float fv[4][8];
#pragma unroll
    for (int i = 0; i < 4; ++i) {
      const float* s = feat + (size_t)(rbase + i) * FDIM + c8;
      float4 x = ((const float4*)s)[0], y = ((const float4*)s)[1];
      fv[i][0] = x.x; fv[i][1] = x.y; fv[i][2] = x.z; fv[i][3] = x.w;
      fv[i][4] = y.x; fv[i][5] = y.y; fv[i][6] = y.z; fv[i][7] = y.w;
      bhalf8_t o; CVT8(o, x, y);
      *(bhalf8_t*)(featC + (size_t)(rbase + i) * FDIM + c8) = o;
    }
#pragma unroll
    for (int c = 0; c < NCLS; ++c) {
      bhalf8_t wr = *(const bhalf8_t*)&lWf[c * FDIM + c8];
      float wv8[8];
#pragma unroll
      for (int j = 0; j < 8; ++j) wv8[j] = bf2f((unsigned short)wr[j]);
#pragma unroll
      for (int i = 0; i < 4; ++i) {
        float s = acc[i][c];
#pragma unroll
        for (int j = 0; j < 8; ++j) s += fv[i][j] * wv8[j];
        acc[i][c] = s;
      }
    }
  }
#pragma unroll
  for (int i = 0; i < 4; ++i)
#pragma unroll
    for (int c = 0; c < NCLS; ++c) {
      float v = acc[i][c];
      v += __shfl_xor(v, 1, 64);  v += __shfl_xor(v, 2, 64);
      v += __shfl_xor(v, 4, 64);  v += __shfl_xor(v, 8, 64);
      v += __shfl_xor(v, 16, 64); v += __shfl_xor(v, 32, 64);
      acc[i][c] = v;
    }
  if (lane == 0) {
#pragma unroll
    for (int i = 0; i < 4; ++i)
#pragma unroll
      for (int c = 0; c < NCLS; ++c)
        logits[(size_t)(rbase + i) * 16 + c] = acc[i][c] + bfc[c];
  }
}

// ---------------- 256x256 MFMA GEMM, 2 single-barrier windows per K-tile ----------------
// BM=BN=256, BK=64, 512 thr (8 waves 2Mx4N), per-wave 128x64 out, acc[8][4].
// X0: rd all B + A rows 0-63 | stage A0+A1(u+1)->buf^1 | 32 MFMA (rows 0-3) | bar
// X1: rd A rows 64-127      | stage B0+B1(u+2)->buf   | 32 MFMA (rows 4-7) | vmcnt(4) | bar
// Safety: A(u+1)-region readers drained >=1 barrier earlier (iter u-1's X0/X1 lgkm
// waits precede B(u-1,1) < X0(u)). B(u+2)-region readers = X0's rdB, lgkm-complete
// before X0's MFMAs < B(u,0) < X1's stage. vmcnt ledger (induction): at X1's wait,
// in-flight = B(u+1)x4 + A(u+1)x4 + B(u+2)x4 = 12 -> vmcnt(4) completes exactly
// iter u+1's 8. Tail: clamped dummy stages keep counts uniform; vmcnt(0)+BAR after.
// Epilogue: C tile transposed through LDS (128KB = 256x256 bf16) with
// col ^ ((row&7)<<3) swizzle -> 16B/lane coalesced stores.
// MODE 0: +bias +BN sum/sumsq atomics.  MODE 1: plain store.

template<int MODE>
__global__ __launch_bounds__(512, 2) void gemm256_bt(
    const unsigned short* __restrict__ A, const unsigned short* __restrict__ Bw,
    const float* __restrict__ bp,
    unsigned short* __restrict__ Cb,
    float* __restrict__ colsum, float* __restrict__ colsq,
    int K, int lda, int ldb, int ldc, int nby)
{
  __shared__ unsigned short L[2][2][2][8192];   // [buf][A/B][half][128*64] = 128 KiB

  const int t = threadIdx.x;
  const int lane = t & 63;
  const int wv = t >> 6;
  const int m = lane & 15, quad = lane >> 4;
  const int wm = wv >> 2, wn = wv & 3;

  // T1 (row-panel form): XCD k owns a contiguous bx-panel group; A L2-resident.
  const int nwg = gridDim.x;
  const int wg = ((blockIdx.x & 7) * (nwg >> 3)) + (blockIdx.x >> 3);
  const int bx = wg / nby;
  const int by = wg - bx * nby;
  const int rowBase = bx << 8;
  const int colBase = by << 8;

  // ds_read fragment offsets (shorts): row group r=16x+m, slot = chunk^(m&7)
  const int bO = (wn & 1) << 12;          // B 64-row subregion offset (64*64 shorts)
  const int ofs0 = m * 64 + ((quad ^ (m & 7)) << 3);   // k-slice 0: chunk quad
  const int ofs1 = ofs0 ^ 32;                          // k-slice 1: chunk quad+4

  // staging: slot s = i*512 + t; r = s>>3, stored chunk = (s&7)^(r&7)
  const int r0 = t >> 3;
  const int q8 = ((t ^ r0) & 7) << 3;     // source chunk element offset in row
  const int ldD = t << 3;                 // LDS dest (shorts); second issue +4096
  const unsigned int aOff =
      (unsigned int)(rowBase + r0) * (unsigned int)lda + (unsigned int)q8;
  const unsigned int bOff00 = (unsigned int)(colBase + r0) * (unsigned int)ldb + q8;
  const unsigned int bOff01 = (unsigned int)(colBase + 64 + r0) * (unsigned int)ldb + q8;
  const unsigned int bOff10 = (unsigned int)(colBase + 128 + r0) * (unsigned int)ldb + q8;
  const unsigned int bOff11 = (unsigned int)(colBase + 192 + r0) * (unsigned int)ldb + q8;

#define STAGEA0(b, kb) do { \
    gl_lds16(A + aOff + (unsigned int)(kb), &L[b][0][0][ldD]); \
    gl_lds16(A + aOff + (unsigned int)(64 * lda) + (unsigned int)(kb), &L[b][0][0][ldD + 4096]); \
  } while (0)
#define STAGEA1(b, kb) do { \
    gl_lds16(A + aOff + (unsigned int)(128 * lda) + (unsigned int)(kb), &L[b][0][1][ldD]); \
    gl_lds16(A + aOff + (unsigned int)(192 * lda) + (unsigned int)(kb), &L[b][0][1][ldD + 4096]); \
  } while (0)
#define STAGEB0(b, kb) do { \
    gl_lds16(Bw + bOff00 + (unsigned int)(kb), &L[b][1][0][ldD]); \
    gl_lds16(Bw + bOff01 + (unsigned int)(kb), &L[b][1][0][ldD + 4096]); \
  } while (0)
#define STAGEB1(b, kb) do { \
    gl_lds16(Bw + bOff10 + (unsigned int)(kb), &L[b][1][1][ldD]); \
    gl_lds16(Bw + bOff11 + (unsigned int)(kb), &L[b][1][1][ldD + 4096]); \
  } while (0)

#define RDA(v, roff) \
    v##_0 = *(const bhalf8_t*)&LA[(roff) + ofs0]; \
    v##_1 = *(const bhalf8_t*)&LA[(roff) + ofs1];
#define RDB(v, roff) \
    v##_0 = *(const bhalf8_t*)&LB[(roff) + ofs0]; \
    v##_1 = *(const bhalf8_t*)&LB[(roff) + ofs1];
#define MM(i, j, av, bv) \
    acc[i][j] = __builtin_amdgcn_mfma_f32_16x16x32_bf16(av##_0, bv##_0, acc[i][j], 0, 0, 0); \
    acc[i][j] = __builtin_amdgcn_mfma_f32_16x16x32_bf16(av##_1, bv##_1, acc[i][j], 0, 0, 0);

  f32x4_t acc[8][4];
#pragma unroll
  for (int i = 0; i < 8; ++i)
#pragma unroll
    for (int j = 0; j < 4; ++j) acc[i][j] = (f32x4_t){0.f, 0.f, 0.f, 0.f};

  const int NT = K >> 6;

  // prologue: tile0 fully -> buf0; B of tile1 -> buf1. vmcnt(4) completes tile0.
  STAGEA0(0, 0);
  STAGEA1(0, 0);
  STAGEB0(0, 0);
  STAGEB1(0, 0);
  {
    const int kb1 = (NT > 1) ? 64 : 0;
    STAGEB0(1, kb1);
    STAGEB1(1, kb1);
  }
  asm volatile("s_waitcnt vmcnt(4)" ::: "memory");
  BAR();

  for (int u = 0; u < NT; ++u) {
    const int buf = u & 1;
    const unsigned short* LA = &L[buf][0][wm][0];
    const unsigned short* LB = &L[buf][1][wn >> 1][bO];
    const int kbA = (u + 1 < NT) ? (u + 1) << 6 : 0;   // tail: clamped dummy
    const int kbB = (u + 2 < NT) ? (u + 2) << 6 : 0;

    bhalf8_t a0_0, a0_1, a1_0, a1_1, a2_0, a2_1, a3_0, a3_1;
    bhalf8_t b0_0, b0_1, b1_0, b1_1, b2_0, b2_1, b3_0, b3_1;

    // ---- X0: rd all B + A rows 0..63; stage A0+A1(u+1); MFMA rows 0-3 ----
    RDB(b0, 0);     RDB(b1, 1024);  RDB(b2, 2048);  RDB(b3, 3072);
    RDA(a0, 0);     RDA(a1, 1024);  RDA(a2, 2048);  RDA(a3, 3072);
    if (buf) { STAGEA0(0, kbA); STAGEA1(0, kbA); }
    else     { STAGEA0(1, kbA); STAGEA1(1, kbA); }
    __builtin_amdgcn_s_setprio(1);
    MM(0, 0, a0, b0); MM(0, 1, a0, b1); MM(0, 2, a0, b2); MM(0, 3, a0, b3);
    MM(1, 0, a1, b0); MM(1, 1, a1, b1); MM(1, 2, a1, b2); MM(1, 3, a1, b3);
    MM(2, 0, a2, b0); MM(2, 1, a2, b1); MM(2, 2, a2, b2); MM(2, 3, a2, b3);
    MM(3, 0, a3, b0); MM(3, 1, a3, b1); MM(3, 2, a3, b2); MM(3, 3, a3, b3);
    __builtin_amdgcn_s_setprio(0);
    BAR();

    // ---- X1: rd A rows 64..127 (reuse a-regs); stage B0+B1(u+2); MFMA rows 4-7 ----
    RDA(a0, 4096);  RDA(a1, 5120);  RDA(a2, 6144);  RDA(a3, 7168);
    if (buf) { STAGEB0(1, kbB); STAGEB1(1, kbB); }
    else     { STAGEB0(0, kbB); STAGEB1(0, kbB); }
    __builtin_amdgcn_s_setprio(1);
    MM(4, 0, a0, b0); MM(4, 1, a0, b1); MM(4, 2, a0, b2); MM(4, 3, a0, b3);
    MM(5, 0, a1, b0); MM(5, 1, a1, b1); MM(5, 2, a1, b2); MM(5, 3, a1, b3);
    MM(6, 0, a2, b0); MM(6, 1, a2, b1); MM(6, 2, a2, b2); MM(6, 3, a2, b3);
    MM(7, 0, a3, b0); MM(7, 1, a3, b1); MM(7, 2, a3, b2); MM(7, 3, a3, b3);
    __builtin_amdgcn_s_setprio(0);
    asm volatile("s_waitcnt vmcnt(4)" ::: "memory");
    BAR();
  }
  asm volatile("s_waitcnt vmcnt(0)" ::: "memory");   // drain tail dummies
  BAR();                                             // ALL waves drained before LDS reuse

#undef STAGEA0
#undef STAGEA1
#undef STAGEB0
#undef STAGEB1
#undef RDA
#undef RDB
#undef MM

  // ---- epilogue: transpose C tile through LDS, store 16B/lane coalesced ----
  // C/D frag layout: row = wm*128 + mi*16 + quad*4 + r, col = wn*64 + ni*16 + m.
  // LDS slot (shorts): row*256 + (col ^ ((row&7)<<3)) -> b16 writes 2-way (free),
  // b128 reads conflict-free, bijective per 8-row stripe.
  unsigned short* Lc = &L[0][0][0][0];   // 131072 B == 256x256 bf16
  if (MODE == 0) {
#pragma unroll
    for (int ni = 0; ni < 4; ++ni) {
      const int lcol = wn * 64 + ni * 16 + m;
      const int gcol = colBase + lcol;
      const float bv = bp[gcol];
      float s = 0.f, qq = 0.f;
#pragma unroll
      for (int mi = 0; mi < 8; ++mi) {
        const int lrow0 = wm * 128 + mi * 16 + quad * 4;
#pragma unroll
        for (int r = 0; r < 4; ++r) {
          float v = acc[mi][ni][r] + bv;
          const int lrow = lrow0 + r;
          Lc[lrow * 256 + (lcol ^ ((lrow & 7) << 3))] = f2bf(v);
          s += v; qq += v * v;
        }
      }
      s += __shfl_xor(s, 16, 64); s += __shfl_xor(s, 32, 64);
      qq += __shfl_xor(qq, 16, 64); qq += __shfl_xor(qq, 32, 64);
      if (quad == 0) { atomicAdd(&colsum[gcol], s); atomicAdd(&colsq[gcol], qq); }
    }
  } else {
#pragma unroll
    for (int ni = 0; ni < 4; ++ni) {
      const int lcol = wn * 64 + ni * 16 + m;
#pragma unroll
      for (int mi = 0; mi < 8; ++mi) {
        const int lrow0 = wm * 128 + mi * 16 + quad * 4;
#pragma unroll
        for (int r = 0; r < 4; ++r) {
          const int lrow = lrow0 + r;
          Lc[lrow * 256 + (lcol ^ ((lrow & 7) << 3))] = f2bf(acc[mi][ni][r]);
        }
      }
    }
  }
  asm volatile("s_waitcnt lgkmcnt(0)" ::: "memory");
  BAR();
  // 16 iters x 512 thr x 16B = 128KB; lanes -> consecutive 16B chunks (coalesced)
#pragma unroll
  for (int i = 0; i < 16; ++i) {
    const int s = i * 512 + t;
    const int tr = s >> 5;            // tile row 0..255
    const int c16 = s & 31;           // 16B chunk 0..31
    bhalf8_t vv = *(const bhalf8_t*)&Lc[tr * 256 + ((c16 ^ (tr & 7)) << 3)];
    *(bhalf8_t*)&Cb[(size_t)(rowBase + tr) * (size_t)ldc + (size_t)(colBase + (c16 << 3))] = vv;
  }
}

// ---------------- BatchNorm: fused finalize + apply, 4 rows/thread ----------------
__global__ void bn_apply(unsigned short* __restrict__ hb,
                         const float* __restrict__ cs, const float* __restrict__ cq,
                         const float* __restrict__ g, const float* __restrict__ bt) {
  int t = blockIdx.x * 256 + threadIdx.x;   // grid 4096 -> 1,048,576 threads
  int c8 = (t & 255) << 3;
  int row0 = t >> 8;                        // 0..4095
  const float inv = 1.f / (float)BROWS;
  float scv[8], shv[8];
#pragma unroll
  for (int j = 0; j < 8; ++j) {
    float mu = cs[c8 + j] * inv;
    float va = cq[c8 + j] * inv - mu * mu;
    float s = g[c8 + j] * rsqrtf(va + 1e-5f);
    scv[j] = s;
    shv[j] = bt[c8 + j] - mu * s;
  }
#pragma unroll
  for (int rr = 0; rr < 4; ++rr) {
    unsigned short* p = hb + (size_t)(row0 + rr * 4096) * FDIM + c8;
    bhalf8_t v = *(bhalf8_t*)p;
    bhalf8_t o;
#pragma unroll
    for (int j = 0; j < 8; ++j)
      o[j] = f2bf(fmaxf(bf2f((unsigned short)v[j]) * scv[j] + shv[j], 0.f));
    *(bhalf8_t*)p = o;
  }
}

// ---------------- attention epilogue: one wave per row ----------------
__global__ __launch_bounds__(256) void attn_ep(
    const unsigned short* __restrict__ qk, const float* __restrict__ logits,
    const float* __restrict__ gamma, float* __restrict__ out)
{
  const int lane = threadIdx.x & 63;
  const int wv = threadIdx.x >> 6;
  const int b = blockIdx.x * 4 + wv;
  const int m = lane & 15, quad = lane >> 4;
  const unsigned short* qrow = qk + (size_t)b * QKN;
  f32x4_t acc = (f32x4_t){0.f, 0.f, 0.f, 0.f};
#pragma unroll
  for (int ks = 0; ks < 2; ++ks) {
    bhalf8_t af = {0,0,0,0,0,0,0,0}, bf = {0,0,0,0,0,0,0,0};
    if (m < NCLS) {
      af = *(const bhalf8_t*)(qrow + m * 64 + ks * 32 + quad * 8);
      bf = *(const bhalf8_t*)(qrow + 896 + m * 64 + ks * 32 + quad * 8);
    }
    acc = __builtin_amdgcn_mfma_f32_16x16x32_bf16(af, bf, acc, 0, 0, 0);
  }
  float logit_e = (m < NCLS) ? logits[(size_t)b * 16 + m] : 0.f;
  float sig = 1.f / (1.f + __expf(-logit_e));
  float corr[4];
#pragma unroll
  for (int r = 0; r < 4; ++r) {
    int c = quad * 4 + r;
    float diag = __shfl(acc[r], (lane & 48) + c, 64);
    float a = acc[r] - diag;
    float av = (m < NCLS) ? fabsf(a) : 0.f;
    av = fmaxf(av, __shfl_xor(av, 1, 64));
    av = fmaxf(av, __shfl_xor(av, 2, 64));
    av = fmaxf(av, __shfl_xor(av, 4, 64));
    av = fmaxf(av, __shfl_xor(av, 8, 64));
    float v = (m < NCLS) ? (a / av) * sig : 0.f;
    v += __shfl_xor(v, 1, 64);
    v += __shfl_xor(v, 2, 64);
    v += __shfl_xor(v, 4, 64);
    v += __shfl_xor(v, 8, 64);
    corr[r] = v;
  }
  if (m == 0) {
#pragma unroll
    for (int r = 0; r < 4; ++r) {
      int c = quad * 4 + r;
      if (c < NCLS) {
        float lc = logits[(size_t)b * 16 + c];
        out[(size_t)b * NCLS + c] = lc + gamma[c] * corr[r];
      }
    }
  }
}

// ---------------- launch ----------------

extern "C" void kernel_launch(void* const* d_in, const int* in_sizes, int n_in,
                              void* d_out, int out_size, void* d_ws, size_t ws_size,
                              hipStream_t stream) {
  const float* features = (const float*)d_in[0];
  const float* W_proj   = (const float*)d_in[1];
  const float* b_proj   = (const float*)d_in[2];
  const float* bn_gamma = (const float*)d_in[3];
  const float* bn_beta  = (const float*)d_in[4];
  const float* W_qk     = (const float*)d_in[5];
  const float* gamma    = (const float*)d_in[6];
  const float* W_fc     = (const float*)d_in[7];
  const float* b_fc     = (const float*)d_in[8];
  float* out = (float*)d_out;

  char* ws = (char*)d_ws;
  unsigned short* featC   = (unsigned short*)ws;                  //  67,108,864 B
  unsigned short* WpC     = (unsigned short*)(ws + 67108864);     //   8,388,608 B
  unsigned short* WqkC    = (unsigned short*)(ws + 75497472);     //   7,340,032 B (contiguous after WpC)
  unsigned short* hbuf    = (unsigned short*)(ws + 82894848);     //  67,108,864 B
  unsigned short* qkC     = (unsigned short*)(ws + 150003712);    //  58,720,256 B
  float*          logitsB = (float*)(ws + 208723968);             //   1,048,576 B
  float*          colsum  = (float*)(ws + 209772544);             //       8,192 B
  float*          colsq   = (float*)(ws + 209780736);             //       8,192 B (end 209,788,928)

  // fused prep: weights cast + features cast + logits + colsum/colsq zero
  prep_fused<<<1024, 256, 0, stream>>>(
      features, W_proj, W_qk, W_fc, b_fc, featC, WpC, logitsB, colsum);

  // GEMM1: h[B,2048] bf16 (+bias +BN stats atomics); grid 64x8 = 512 = 2.0 rounds
  gemm256_bt<0><<<512, 512, 0, stream>>>(
      featC, WpC, b_proj, hbuf, colsum, colsq, FDIM, FDIM, FDIM, FDIM, 8);

  // BN finalize+apply (relu) in-place on bf16 h
  bn_apply<<<4096, 256, 0, stream>>>(hbuf, colsum, colsq, bn_gamma, bn_beta);

  // GEMM2: qk[B,1792] bf16 = h @ W_qk^T; grid 64x7 = 448
  gemm256_bt<1><<<448, 512, 0, stream>>>(
      hbuf, WqkC, nullptr, qkC, nullptr, nullptr, FDIM, FDIM, FDIM, QKN, 7);

  // attention epilogue (one wave per row)
  attn_ep<<<BROWS / 4, 256, 0, stream>>>(qkC, logitsB, gamma, out);
}